// Round 7
// baseline (577.881 us; speedup 1.0000x reference)
//
#include <hip/hip_runtime.h>
#include <hip/hip_bf16.h>

// LinearGaussianSystem via Woodbury:
//   M  = R + H Pinv H^T                (16x16, per batch)
//   Sigma = Pinv - G^T W,  W = M^-1 G, G = H Pinv   (Pinv symmetric => Gt = G^T)
//   mu = mu0 + W^T (y - c),  c = bias + H mu0
// 16-lane scheme: lane t (of each 16-group) owns M column t and W columns t, t+16.
// 4 batches per wave -> the 16 ds_swizzle broadcasts per GJ step serve 4 batches.
// Sigma epilogue on MFMA (bf16): D = A*B + C, A = -0.5*Gt k-duplicated, B = W
// k-duplicated the same way, C = Pinv fragment  => D = Pinv - Gt*W.
//
// ws layout (floats):
//   0    : Acm[16][16]  A=(H Pinv)H^T column-major
//   256  : gcm[32][16]  G columns as rows
//   768  : af[2][64][4] A-frags, packed bf16 pairs (uint), tile r=0,1
//   1280 : pf[4][64][4] Pinv D-layout frags, tile t=(r*2+c)
//   2816 : cvec[16]     bias + H mu0
//   2832 : m0v[32]      mu0

typedef __attribute__((ext_vector_type(8))) short bf16x8;
typedef __attribute__((ext_vector_type(4))) float f32x4;

__device__ __forceinline__ unsigned bf16rne(float f) {
    unsigned x = __float_as_uint(f);
    return (x + 0x7FFFu + ((x >> 16) & 1u)) >> 16;
}

__global__ void lgs_setup(const float* __restrict__ H, const float* __restrict__ bias,
                          const float* __restrict__ mu0, const float* __restrict__ P,
                          float* __restrict__ ws)
{
    __shared__ float aug[32][65];   // [P | I] augmented, padded stride 65
    __shared__ float colk[32];
    __shared__ float Gs[16][32];    // G = H Pinv
    __shared__ float Gts[32][16];   // Gt = Pinv H^T
    const int tid = threadIdx.x;    // 256 threads

    for (int idx = tid; idx < 2048; idx += 256) {
        int r = idx >> 6, c = idx & 63;
        aug[r][c] = (c < 32) ? P[r * 32 + c] : (((c - 32) == r) ? 1.0f : 0.0f);
    }
    __syncthreads();

    // Gauss-Jordan inversion of P (SPD -> no pivoting). Thread tid<64 owns column tid.
    for (int k = 0; k < 32; ++k) {
        if (tid < 32) colk[tid] = aug[tid][k];
        __syncthreads();
        if (tid < 64) {
            float rk = aug[k][tid] * (1.0f / colk[k]);
            aug[k][tid] = rk;
            for (int r = 0; r < 32; ++r)
                if (r != k) aug[r][tid] -= colk[r] * rk;
        }
        __syncthreads();
    }
    // Pinv[r][c] = aug[r][32+c]

    for (int idx = tid; idx < 512; idx += 256) {
        int o = idx >> 5, s = idx & 31;
        float acc = 0.f;
        for (int v = 0; v < 32; ++v) acc += H[o * 32 + v] * aug[v][32 + s];
        Gs[o][s] = acc;
    }
    for (int idx = tid; idx < 512; idx += 256) {
        int s = idx >> 4, o = idx & 15;
        float acc = 0.f;
        for (int v = 0; v < 32; ++v) acc += aug[s][32 + v] * H[o * 32 + v];
        Gts[s][o] = acc;
    }
    __syncthreads();

    for (int idx = tid; idx < 256; idx += 256) {      // Acm[j][i] = A[i][j]
        int j = idx >> 4, i = idx & 15;
        float acc = 0.f;
        for (int s = 0; s < 32; ++s) acc += Gs[i][s] * H[j * 32 + s];
        ws[idx] = acc;
    }
    for (int idx = tid; idx < 512; idx += 256) {      // gcm[s][o] = G[o][s]
        int s = idx >> 4, o = idx & 15;
        ws[256 + idx] = Gs[o][s];
    }
    // A-frags: af[r][l][j] = pack(-0.5*Gt[16r+(l&15)][kb], -0.5*Gt[...][kb+1])
    // with kb = ((l>>4)*8 + 2j) & 15  (k duplicated across halves)
    {
        unsigned* wsu = (unsigned*)ws;
        for (int idx = tid; idx < 512; idx += 256) {
            int r = idx >> 8, rem = idx & 255;
            int l = rem >> 2, j = rem & 3;
            int mm = 16 * r + (l & 15);
            int kb = (((l >> 4) * 8) + 2 * j) & 15;
            float v0 = -0.5f * Gts[mm][kb];
            float v1 = -0.5f * Gts[mm][kb + 1];
            wsu[768 + idx] = bf16rne(v0) | (bf16rne(v1) << 16);
        }
    }
    // Pinv frags in MFMA C/D layout: pf[t][l][j] = Pinv[16*(t>>1)+((l>>4)*4)+j][16*(t&1)+(l&15)]
    for (int idx = tid; idx < 1024; idx += 256) {
        int tt = idx >> 8, rem = idx & 255;
        int l = rem >> 2, j = rem & 3;
        int row = 16 * (tt >> 1) + ((l >> 4) << 2) + j;
        int col = 16 * (tt & 1) + (l & 15);
        ws[1280 + idx] = aug[row][32 + col];
    }
    if (tid < 16) {
        float acc = bias[tid];
        for (int s = 0; s < 32; ++s) acc += H[tid * 32 + s] * mu0[s];
        ws[2816 + tid] = acc;
    }
    if (tid < 32) ws[2832 + tid] = mu0[tid];
}

// Broadcast x from lane K of each 16-lane group: BitMode offset = (or<<5)|and,
// and=0x10 keeps the group bit within the 32-half, or=K -> src = (lane&0x10)|K.
#define BCAST16(x, K) __int_as_float(__builtin_amdgcn_ds_swizzle(__float_as_int(x), (((K) << 5) | 0x10)))

// Column-wise GJ solve step, 16 lanes/batch. Lane t owns M column t and RHS
// columns t, t+16. After 16 steps, w0 = W[:,t], w1 = W[:,t+16].
template <int K>
__device__ __forceinline__ void gj16(int t, float (&m)[16], float (&w0)[16],
                                     float (&w1)[16])
{
    if (t == K) m[K] = 1.0f / m[K];   // column owner publishes inv-pivot in slot K
    float bc[16];
#pragma unroll
    for (int i = 0; i < 16; ++i) bc[i] = BCAST16(m[i], K);
    // bc[K] = 1/pivot, bc[i!=K] = pivot-column entry m[i][K]
    if (t > K) {                      // future pivot columns of M
        float pk = m[K] * bc[K];
        m[K] = pk;
#pragma unroll
        for (int i = 0; i < 16; ++i)
            if (i != K) m[i] -= bc[i] * pk;
    }
    float a0 = w0[K] * bc[K];
    float a1 = w1[K] * bc[K];
    w0[K] = a0; w1[K] = a1;
#pragma unroll
    for (int i = 0; i < 16; ++i) {
        if (i != K) {
            w0[i] -= bc[i] * a0;
            w1[i] -= bc[i] * a1;
        }
    }
}

__global__ __launch_bounds__(512, 4) void lgs_main(
    const float* __restrict__ obs, const float* __restrict__ noise,
    const float* __restrict__ ws,
    float* __restrict__ out_mean, float* __restrict__ out_cov, int B)
{
    // W staging: [32 slots][32 cols][16 k], XOR-swizzled k. 64 KB, wave-private slices.
    __shared__ float ld[16384];

    const int tid = threadIdx.x;
    const int l   = tid & 63;                        // lane
    const int t   = tid & 15;                        // column owner (M col t; W cols t,t+16)
    const int grp = tid >> 4;                        // batch slot in block (0..31)
    const int wv  = tid >> 6;                        // wave in block (0..7)
    const int b   = blockIdx.x * 32 + grp;
    const int bb  = (b < B) ? b : (B - 1);           // clamp (keeps waves full)

    const float* __restrict__ Acm  = ws;             // [16][16]
    const float* __restrict__ gcm  = ws + 256;       // [32][16]
    const float* __restrict__ cvec = ws + 2816;      // [16]
    const float* __restrict__ m0v  = ws + 2832;      // [32]

    float m[16], w0[16], w1[16];

    // M column t = R column t + A column t (R symmetric -> read row t, contiguous).
    const float4* Rr = (const float4*)(noise + (size_t)bb * 256 + t * 16);
    const float4* Ar = (const float4*)(Acm + t * 16);
#pragma unroll
    for (int i = 0; i < 4; ++i) {
        float4 r = Rr[i], a = Ar[i];
        m[4*i+0] = r.x + a.x; m[4*i+1] = r.y + a.y;
        m[4*i+2] = r.z + a.z; m[4*i+3] = r.w + a.w;
    }
    // RHS columns: w0 = G[:,t], w1 = G[:,t+16]
    const float4* G0 = (const float4*)(gcm + t * 16);
    const float4* G1 = (const float4*)(gcm + (t + 16) * 16);
#pragma unroll
    for (int i = 0; i < 4; ++i) {
        float4 g0 = G0[i];
        w0[4*i+0] = g0.x; w0[4*i+1] = g0.y; w0[4*i+2] = g0.z; w0[4*i+3] = g0.w;
        float4 g1 = G1[i];
        w1[4*i+0] = g1.x; w1[4*i+1] = g1.y; w1[4*i+2] = g1.z; w1[4*i+3] = g1.w;
    }

    gj16<0>(t, m, w0, w1);   gj16<1>(t, m, w0, w1);
    gj16<2>(t, m, w0, w1);   gj16<3>(t, m, w0, w1);
    gj16<4>(t, m, w0, w1);   gj16<5>(t, m, w0, w1);
    gj16<6>(t, m, w0, w1);   gj16<7>(t, m, w0, w1);
    gj16<8>(t, m, w0, w1);   gj16<9>(t, m, w0, w1);
    gj16<10>(t, m, w0, w1);  gj16<11>(t, m, w0, w1);
    gj16<12>(t, m, w0, w1);  gj16<13>(t, m, w0, w1);
    gj16<14>(t, m, w0, w1);  gj16<15>(t, m, w0, w1);

    // posterior mean (local): mu[s] = mu0[s] + sum_o W[o][s] * (y - c)[o], s = t, t+16
    {
        float mu0r = m0v[t], mu1r = m0v[t + 16];
        const float4* Y4 = (const float4*)(obs + (size_t)bb * 16);
        const float4* C4 = (const float4*)cvec;
#pragma unroll
        for (int i = 0; i < 4; ++i) {
            float4 y = Y4[i], c = C4[i];
            float d0 = y.x - c.x, d1 = y.y - c.y, d2 = y.z - c.z, d3 = y.w - c.w;
            mu0r += w0[4*i+0] * d0 + w0[4*i+1] * d1 + w0[4*i+2] * d2 + w0[4*i+3] * d3;
            mu1r += w1[4*i+0] * d0 + w1[4*i+1] * d1 + w1[4*i+2] * d2 + w1[4*i+3] * d3;
        }
        if (b < B) {
            out_mean[(size_t)b * 32 + t]      = mu0r;
            out_mean[(size_t)b * 32 + t + 16] = mu1r;
        }
    }

    // Stage W into LDS (wave-private slice; same-wave DS is in-order -> no barrier).
    // k' = k ^ ((col&3)<<2); note (t+16)&3 == t&3, so one xw serves both columns.
    {
        const int xw = (t & 3) << 2;
        float* wb0 = &ld[grp * 512 + t * 16];
        float* wb1 = &ld[grp * 512 + (t + 16) * 16];
        *(float4*)&wb0[ 0 ^ xw] = make_float4(w0[0],  w0[1],  w0[2],  w0[3]);
        *(float4*)&wb0[ 4 ^ xw] = make_float4(w0[4],  w0[5],  w0[6],  w0[7]);
        *(float4*)&wb0[ 8 ^ xw] = make_float4(w0[8],  w0[9],  w0[10], w0[11]);
        *(float4*)&wb0[12 ^ xw] = make_float4(w0[12], w0[13], w0[14], w0[15]);
        *(float4*)&wb1[ 0 ^ xw] = make_float4(w1[0],  w1[1],  w1[2],  w1[3]);
        *(float4*)&wb1[ 4 ^ xw] = make_float4(w1[4],  w1[5],  w1[6],  w1[7]);
        *(float4*)&wb1[ 8 ^ xw] = make_float4(w1[8],  w1[9],  w1[10], w1[11]);
        *(float4*)&wb1[12 ^ xw] = make_float4(w1[12], w1[13], w1[14], w1[15]);
    }

    // Constant frags (lane-indexed, L1-hot)
    const uint4*  AF4 = (const uint4*) (ws + 768);
    const float4* PF4 = (const float4*)(ws + 1280);
    uint4 a0u = AF4[l], a1u = AF4[64 + l];
    bf16x8 A0, A1;
    __builtin_memcpy(&A0, &a0u, 16);
    __builtin_memcpy(&A1, &a1u, 16);
    f32x4 pfr[4];
#pragma unroll
    for (int tt = 0; tt < 4; ++tt) {
        float4 p = PF4[tt * 64 + l];
        pfr[tt][0] = p.x; pfr[tt][1] = p.y; pfr[tt][2] = p.z; pfr[tt][3] = p.w;
    }

    const int k0 = ((l >> 4) * 8) & 15;   // k-dup: groups 2,3 re-read 0..15
    const int xr = (l & 3) << 2;
#pragma unroll
    for (int h = 0; h < 4; ++h) {
        const int bh = blockIdx.x * 32 + wv * 4 + h;
        const int rbase = (wv * 4 + h) * 512 + (l & 15) * 16;
#pragma unroll
        for (int c = 0; c < 2; ++c) {
            const float* rb = &ld[rbase + c * 256];
            float4 f0 = *(const float4*)&rb[(k0    ) ^ xr];
            float4 f1 = *(const float4*)&rb[(k0 + 4) ^ xr];
            __hip_bfloat162 q0 = __float22bfloat162_rn(make_float2(f0.x, f0.y));
            __hip_bfloat162 q1 = __float22bfloat162_rn(make_float2(f0.z, f0.w));
            __hip_bfloat162 q2 = __float22bfloat162_rn(make_float2(f1.x, f1.y));
            __hip_bfloat162 q3 = __float22bfloat162_rn(make_float2(f1.z, f1.w));
            unsigned bu[4];
            __builtin_memcpy(&bu[0], &q0, 4);
            __builtin_memcpy(&bu[1], &q1, 4);
            __builtin_memcpy(&bu[2], &q2, 4);
            __builtin_memcpy(&bu[3], &q3, 4);
            bf16x8 Bf;
            __builtin_memcpy(&Bf, bu, 16);
#pragma unroll
            for (int r = 0; r < 2; ++r) {
                f32x4 d = __builtin_amdgcn_mfma_f32_16x16x32_bf16(
                    r ? A1 : A0, Bf, pfr[r * 2 + c], 0, 0, 0);
                if (bh < B) {
                    float* S = out_cov + (size_t)bh * 1024
                             + (16 * r + ((l >> 4) << 2)) * 32 + 16 * c + (l & 15);
                    S[0]  = d[0];
                    S[32] = d[1];
                    S[64] = d[2];
                    S[96] = d[3];
                }
            }
        }
    }
}

extern "C" void kernel_launch(void* const* d_in, const int* in_sizes, int n_in,
                              void* d_out, int out_size, void* d_ws, size_t ws_size,
                              hipStream_t stream)
{
    const float* obs   = (const float*)d_in[0];   // [B,16]
    const float* noise = (const float*)d_in[1];   // [B,16,16]
    const float* H     = (const float*)d_in[2];   // [16,32]
    const float* bias  = (const float*)d_in[3];   // [16]
    const float* mu0   = (const float*)d_in[4];   // [32]
    const float* P     = (const float*)d_in[5];   // [32,32]
    float* ws = (float*)d_ws;

    const int B = in_sizes[0] / 16;
    float* out_mean = (float*)d_out;
    float* out_cov  = out_mean + (size_t)B * 32;

    lgs_setup<<<1, 256, 0, stream>>>(H, bias, mu0, P, ws);
    lgs_main<<<(B + 31) / 32, 512, 0, stream>>>(obs, noise, ws, out_mean, out_cov, B);
}

// Round 8
// 115.416 us; speedup vs baseline: 5.0069x; 5.0069x over previous
//
#include <hip/hip_runtime.h>
#include <hip/hip_bf16.h>

// LinearGaussianSystem via Woodbury:
//   M  = R + H Pinv H^T                  (16x16, per batch)
//   Q  = M^-1  (computed per batch via column-GJ on [M | I], 16 lanes/batch)
//   T  = Q G               (stage-1 MFMA: A = Q bf16, B = 0.5*G const, k-dup)
//   Sigma = Pinv - G^T T   (stage-2 MFMA: A = -0.5*Gt const, B = T bf16, C = Pinv)
//   mu = mu0 + T^T z, z = y - c  (from stage-1 fp32 D + xor16/xor32 reduce)
// 4 batches/wave: the 16 ds_swizzle broadcasts per GJ step serve 4 batches.
// No __syncthreads in lgs_main: each wave only touches its own LDS slots.
//
// ws layout (floats / u32):
//   0    : Acm[16][16]   A=(H Pinv)H^T column-major
//   768  : af[2][64][4]  stage-2 A-frags (-0.5*Gt, k-dup), packed bf16 pairs
//   1280 : pf[4][64][4]  Pinv C/D-layout frags, tile t=(r*2+c)
//   2304 : bgf[2][64][4] stage-1 B-frags (0.5*G, k-dup), packed bf16 pairs
//   2816 : cvec[16]      bias + H mu0
//   2832 : m0v[32]       mu0

typedef __attribute__((ext_vector_type(8))) short bf16x8;
typedef __attribute__((ext_vector_type(4))) float f32x4;

__device__ __forceinline__ unsigned bf16rne(float f) {
    unsigned x = __float_as_uint(f);
    return (x + 0x7FFFu + ((x >> 16) & 1u)) >> 16;
}
__device__ __forceinline__ unsigned pack2(float a, float b) {
    return bf16rne(a) | (bf16rne(b) << 16);
}

__global__ void lgs_setup(const float* __restrict__ H, const float* __restrict__ bias,
                          const float* __restrict__ mu0, const float* __restrict__ P,
                          float* __restrict__ ws)
{
    __shared__ float aug[32][65];   // [P | I] augmented, padded stride 65
    __shared__ float colk[32];
    __shared__ float Gs[16][32];    // G  = H Pinv
    __shared__ float Gts[32][16];   // Gt = Pinv H^T
    const int tid = threadIdx.x;    // 256 threads

    for (int idx = tid; idx < 2048; idx += 256) {
        int r = idx >> 6, c = idx & 63;
        aug[r][c] = (c < 32) ? P[r * 32 + c] : (((c - 32) == r) ? 1.0f : 0.0f);
    }
    __syncthreads();

    // Gauss-Jordan inversion of P (SPD -> no pivoting). Thread tid<64 owns column tid.
    for (int k = 0; k < 32; ++k) {
        if (tid < 32) colk[tid] = aug[tid][k];
        __syncthreads();
        if (tid < 64) {
            float rk = aug[k][tid] * (1.0f / colk[k]);
            aug[k][tid] = rk;
            for (int r = 0; r < 32; ++r)
                if (r != k) aug[r][tid] -= colk[r] * rk;
        }
        __syncthreads();
    }
    // Pinv[r][c] = aug[r][32+c]

    for (int idx = tid; idx < 512; idx += 256) {
        int o = idx >> 5, s = idx & 31;
        float acc = 0.f;
        for (int v = 0; v < 32; ++v) acc += H[o * 32 + v] * aug[v][32 + s];
        Gs[o][s] = acc;
    }
    for (int idx = tid; idx < 512; idx += 256) {
        int s = idx >> 4, o = idx & 15;
        float acc = 0.f;
        for (int v = 0; v < 32; ++v) acc += aug[s][32 + v] * H[o * 32 + v];
        Gts[s][o] = acc;
    }
    __syncthreads();

    for (int idx = tid; idx < 256; idx += 256) {      // Acm[j][i] = A[i][j]
        int j = idx >> 4, i = idx & 15;
        float acc = 0.f;
        for (int s = 0; s < 32; ++s) acc += Gs[i][s] * H[j * 32 + s];
        ws[idx] = acc;
    }
    unsigned* wsu = (unsigned*)ws;
    // stage-2 A-frags: af[r][l][j] = pack(-0.5*Gt[16r+(l&15)][kb], ..[kb+1]),
    // kb = ((l>>4)*8 + 2j) & 15  (k duplicated across halves)
    for (int idx = tid; idx < 512; idx += 256) {
        int r = idx >> 8, rem = idx & 255;
        int l = rem >> 2, j = rem & 3;
        int mm = 16 * r + (l & 15);
        int kb = (((l >> 4) * 8) + 2 * j) & 15;
        wsu[768 + idx] = pack2(-0.5f * Gts[mm][kb], -0.5f * Gts[mm][kb + 1]);
    }
    // Pinv frags in MFMA C/D layout: pf[t][l][j] = Pinv[16*(t>>1)+((l>>4)*4)+j][16*(t&1)+(l&15)]
    for (int idx = tid; idx < 1024; idx += 256) {
        int tt = idx >> 8, rem = idx & 255;
        int l = rem >> 2, j = rem & 3;
        int row = 16 * (tt >> 1) + ((l >> 4) << 2) + j;
        int col = 16 * (tt & 1) + (l & 15);
        ws[1280 + idx] = aug[row][32 + col];
    }
    // stage-1 B-frags: bgf[c][l][j2] = pack(0.5*G[k][16c+(l&15)], 0.5*G[k+1][16c+(l&15)]),
    // k = ((l>>4)*8 + 2*j2) & 15 (even -> k+1 in range)
    for (int idx = tid; idx < 512; idx += 256) {
        int c = idx >> 8, rem = idx & 255;
        int l = rem >> 2, j2 = rem & 3;
        int col = 16 * c + (l & 15);
        int k = (((l >> 4) * 8) + 2 * j2) & 15;
        wsu[2304 + idx] = pack2(0.5f * Gs[k][col], 0.5f * Gs[k + 1][col]);
    }
    if (tid < 16) {
        float acc = bias[tid];
        for (int s = 0; s < 32; ++s) acc += H[tid * 32 + s] * mu0[s];
        ws[2816 + tid] = acc;
    }
    if (tid < 32) ws[2832 + tid] = mu0[tid];
}

// Broadcast x from lane K of each 16-lane group (BitMode: and=0x10 keeps the
// group bit within each 32-half, or=K). Validated in round 1.
#define BCAST16(x, K) __int_as_float(__builtin_amdgcn_ds_swizzle(__float_as_int(x), (((K) << 5) | 0x10)))

// Column-GJ on [M | I]. Lane t owns M column t and Q column t (starts e_t).
// Same 32-reg sustained state as the proven round-6 gj32 step.
template <int K>
__device__ __forceinline__ void gj16(int t, float (&m)[16], float (&v)[16])
{
    if (t == K) m[K] = 1.0f / m[K];   // owner publishes inv-pivot in slot K
    float bc[16];
#pragma unroll
    for (int i = 0; i < 16; ++i) bc[i] = BCAST16(m[i], K);
    float pk = m[K] * bc[K];          // meaningful for cols t>K; dead elsewhere
#pragma unroll
    for (int i = 0; i < 16; ++i)
        if (i != K) m[i] -= bc[i] * pk;
    m[K] = pk;
    float a = v[K] * bc[K];
#pragma unroll
    for (int i = 0; i < 16; ++i)
        if (i != K) v[i] -= bc[i] * a;
    v[K] = a;
}

__global__ __launch_bounds__(512, 4) void lgs_main(
    const float* __restrict__ obs, const float* __restrict__ noise,
    const float* __restrict__ ws,
    float* __restrict__ out_mean, float* __restrict__ out_cov, int B)
{
    // 32 slots x 256 floats (1 KB): Q staging, then reused for bf16 T. 32 KB.
    __shared__ float ld[8192];

    const int tid  = threadIdx.x;
    const int l    = tid & 63;                       // lane
    const int t    = tid & 15;                       // column owner
    const int slot = tid >> 4;                       // batch slot (0..31)
    const int wv   = tid >> 6;                       // wave (0..7)
    const int b    = blockIdx.x * 32 + slot;
    const int bb   = (b < B) ? b : (B - 1);

    const float* __restrict__ Acm  = ws;
    const float* __restrict__ cvec = ws + 2816;
    const float* __restrict__ m0v  = ws + 2832;

    float m[16], v[16];

    // M column t = R column t + A column t (R symmetric -> read row t, contiguous).
    const float4* Rr = (const float4*)(noise + (size_t)bb * 256 + t * 16);
    const float4* Ar = (const float4*)(Acm + t * 16);
#pragma unroll
    for (int i = 0; i < 4; ++i) {
        float4 r = Rr[i], a = Ar[i];
        m[4*i+0] = r.x + a.x; m[4*i+1] = r.y + a.y;
        m[4*i+2] = r.z + a.z; m[4*i+3] = r.w + a.w;
    }
#pragma unroll
    for (int i = 0; i < 16; ++i) v[i] = (i == t) ? 1.0f : 0.0f;

    gj16<0>(t, m, v);   gj16<1>(t, m, v);   gj16<2>(t, m, v);   gj16<3>(t, m, v);
    gj16<4>(t, m, v);   gj16<5>(t, m, v);   gj16<6>(t, m, v);   gj16<7>(t, m, v);
    gj16<8>(t, m, v);   gj16<9>(t, m, v);   gj16<10>(t, m, v);  gj16<11>(t, m, v);
    gj16<12>(t, m, v);  gj16<13>(t, m, v);  gj16<14>(t, m, v);  gj16<15>(t, m, v);

    // Stage Q col t (quarter-XOR swizzled; wave-private slot, no barrier needed).
    {
        const int xw = t & 3;
        float* wb = &ld[slot * 256 + t * 16];
        *(float4*)&wb[(0 ^ xw) << 2] = make_float4(v[0],  v[1],  v[2],  v[3]);
        *(float4*)&wb[(1 ^ xw) << 2] = make_float4(v[4],  v[5],  v[6],  v[7]);
        *(float4*)&wb[(2 ^ xw) << 2] = make_float4(v[8],  v[9],  v[10], v[11]);
        *(float4*)&wb[(3 ^ xw) << 2] = make_float4(v[12], v[13], v[14], v[15]);
    }

    // Constant frags (L1-hot)
    const uint4*  AF4 = (const uint4*)(ws + 768);
    const uint4*  BG4 = (const uint4*)(ws + 2304);
    const float4* PF4 = (const float4*)(ws + 1280);
    uint4 a0u = AF4[l], a1u = AF4[64 + l];
    uint4 g0u = BG4[l], g1u = BG4[64 + l];
    bf16x8 A0, A1, Bg0, Bg1;
    __builtin_memcpy(&A0,  &a0u, 16);
    __builtin_memcpy(&A1,  &a1u, 16);
    __builtin_memcpy(&Bg0, &g0u, 16);
    __builtin_memcpy(&Bg1, &g1u, 16);
    float4 pq;
    f32x4 pfr0, pfr1, pfr2, pfr3;
    pq = PF4[l];        pfr0[0]=pq.x; pfr0[1]=pq.y; pfr0[2]=pq.z; pfr0[3]=pq.w;
    pq = PF4[64 + l];   pfr1[0]=pq.x; pfr1[1]=pq.y; pfr1[2]=pq.z; pfr1[3]=pq.w;
    pq = PF4[128 + l];  pfr2[0]=pq.x; pfr2[1]=pq.y; pfr2[2]=pq.z; pfr2[3]=pq.w;
    pq = PF4[192 + l];  pfr3[0]=pq.x; pfr3[1]=pq.y; pfr3[2]=pq.z; pfr3[3]=pq.w;

    const int ch = l & 15;           // output column within tile
    const int gp = l >> 4;           // k-group 0..3
    const int gq = (gp & 1) * 2;     // Q quarter base (k duplicated)
    const int xq = ch & 3;           // Q read XOR
    const int xt = (ch & 1) << 2;    // T pair XOR
    const float4 cv = ((const float4*)cvec)[gp];
    const float mu0a = m0v[ch], mu0b = m0v[16 + ch];
    const f32x4 zero = {0.f, 0.f, 0.f, 0.f};

#pragma unroll
    for (int h = 0; h < 4; ++h) {
        const int sh  = wv * 4 + h;                  // this wave's slot
        const int bh  = blockIdx.x * 32 + sh;
        const int bhc = (bh < B) ? bh : (B - 1);

        // Stage-1 A-frag: A[row=ch][k] = Q[ch][k&15] = staged col ch (symmetry)
        const float* qb = &ld[sh * 256 + ch * 16];
        float4 qa = *(const float4*)&qb[((gq    ) ^ xq) << 2];
        float4 qc = *(const float4*)&qb[((gq + 1) ^ xq) << 2];
        unsigned qarr[4] = { pack2(qa.x, qa.y), pack2(qa.z, qa.w),
                             pack2(qc.x, qc.y), pack2(qc.z, qc.w) };
        bf16x8 Qa; __builtin_memcpy(&Qa, qarr, 16);
        f32x4 d0 = __builtin_amdgcn_mfma_f32_16x16x32_bf16(Qa, Bg0, zero, 0, 0, 0);
        f32x4 d1 = __builtin_amdgcn_mfma_f32_16x16x32_bf16(Qa, Bg1, zero, 0, 0, 0);
        // d_c[j] = T_c[row = gp*4+j][col = ch],  T = Q*G

        // posterior mean: mu[16c+ch] = mu0 + sum_i T_c[i][ch] * z[i]
        float4 yv = *(const float4*)(obs + (size_t)bhc * 16 + gp * 4);
        float z0 = yv.x - cv.x, z1 = yv.y - cv.y, z2 = yv.z - cv.z, z3 = yv.w - cv.w;
        float p0 = d0[0]*z0 + d0[1]*z1 + d0[2]*z2 + d0[3]*z3;
        float p1 = d1[0]*z0 + d1[1]*z1 + d1[2]*z2 + d1[3]*z3;
        p0 += __int_as_float(__builtin_amdgcn_ds_swizzle(__float_as_int(p0), 0x401F));
        p1 += __int_as_float(__builtin_amdgcn_ds_swizzle(__float_as_int(p1), 0x401F));
        p0 += __shfl_xor(p0, 32, 64);
        p1 += __shfl_xor(p1, 32, 64);
        if (bh < B) {
            if (gp == 0) out_mean[(size_t)bh * 32 + ch]      = mu0a + p0;
            if (gp == 1) out_mean[(size_t)bh * 32 + 16 + ch] = mu0b + p1;
        }

        // T -> LDS as bf16 pairs (overwrites this slot's Q; same-wave order).
        // Storage convention: u32 position p holds k-pair (p ^ xt).
        unsigned* tb = (unsigned*)&ld[sh * 256];
        const int g2 = gp * 2;
        *(uint2*)&tb[      ch * 8 + (g2 ^ xt)] =
            make_uint2(pack2(d0[0], d0[1]), pack2(d0[2], d0[3]));
        *(uint2*)&tb[128 + ch * 8 + (g2 ^ xt)] =
            make_uint2(pack2(d1[0], d1[1]), pack2(d1[2], d1[3]));

        // Stage-2 B-frag: B[k][col=ch] = T_c[k&15][ch]
        const int kp = (gp & 1) * 4;
        uint4 bu0 = *(const uint4*)&tb[      ch * 8 + (kp ^ xt)];
        uint4 bu1 = *(const uint4*)&tb[128 + ch * 8 + (kp ^ xt)];
        bf16x8 Bf0, Bf1;
        __builtin_memcpy(&Bf0, &bu0, 16);
        __builtin_memcpy(&Bf1, &bu1, 16);
        f32x4 s00 = __builtin_amdgcn_mfma_f32_16x16x32_bf16(A0, Bf0, pfr0, 0, 0, 0);
        f32x4 s01 = __builtin_amdgcn_mfma_f32_16x16x32_bf16(A0, Bf1, pfr1, 0, 0, 0);
        f32x4 s10 = __builtin_amdgcn_mfma_f32_16x16x32_bf16(A1, Bf0, pfr2, 0, 0, 0);
        f32x4 s11 = __builtin_amdgcn_mfma_f32_16x16x32_bf16(A1, Bf1, pfr3, 0, 0, 0);

        if (bh < B) {
            float* Sb = out_cov + (size_t)bh * 1024 + (gp * 4) * 32 + ch;
#pragma unroll
            for (int j = 0; j < 4; ++j) {
                Sb[j * 32]       = s00[j];
                Sb[j * 32 + 16]  = s01[j];
                Sb[j * 32 + 512] = s10[j];
                Sb[j * 32 + 528] = s11[j];
            }
        }
    }
}

extern "C" void kernel_launch(void* const* d_in, const int* in_sizes, int n_in,
                              void* d_out, int out_size, void* d_ws, size_t ws_size,
                              hipStream_t stream)
{
    const float* obs   = (const float*)d_in[0];   // [B,16]
    const float* noise = (const float*)d_in[1];   // [B,16,16]
    const float* H     = (const float*)d_in[2];   // [16,32]
    const float* bias  = (const float*)d_in[3];   // [16]
    const float* mu0   = (const float*)d_in[4];   // [32]
    const float* P     = (const float*)d_in[5];   // [32,32]
    float* ws = (float*)d_ws;

    const int B = in_sizes[0] / 16;
    float* out_mean = (float*)d_out;
    float* out_cov  = out_mean + (size_t)B * 32;

    lgs_setup<<<1, 256, 0, stream>>>(H, bias, mu0, P, ws);
    lgs_main<<<(B + 31) / 32, 512, 0, stream>>>(obs, noise, ws, out_mean, out_cov, B);
}